// Round 1
// baseline (492.997 us; speedup 1.0000x reference)
//
#include <hip/hip_runtime.h>
#include <hip/hip_bf16.h>

typedef unsigned int uint;
typedef unsigned short ushort;
typedef __attribute__((ext_vector_type(8))) short short8;   // 8 bf16 (4 VGPRs)
typedef __attribute__((ext_vector_type(4))) float f32x4;

#define SCALEF 0.08838834764831845f   // 128^-0.5
#define NBINS 4096
#define CAND_MAX 4096
#define MARGIN 0.08f

static __device__ __forceinline__ ushort f2bf(float f) {
  uint u = __float_as_uint(f);
  uint r = ((u >> 16) & 1u) + 0x7fffu;   // RNE
  return (ushort)((u + r) >> 16);
}

// ---------------- K0: Q/K projection (fp32 -> bf16), one block per (b,l) row ----
__global__ __launch_bounds__(128) void k_proj(const float* __restrict__ x,
    const float* __restrict__ Wq, const float* __restrict__ bq,
    const float* __restrict__ Wk, const float* __restrict__ bk,
    ushort* __restrict__ Qb, ushort* __restrict__ Kb) {
  int bl = blockIdx.x;              // b*1024 + l
  int h = threadIdx.x;              // 0..127
  __shared__ float xs[16];
  if (h < 16) xs[h] = x[(size_t)bl * 16 + h];
  __syncthreads();
  float q = bq[h], k = bk[h];
#pragma unroll
  for (int d = 0; d < 16; d++) {
    float xv = xs[d];
    q += xv * Wq[d * 128 + h];
    k += xv * Wk[d * 128 + h];
  }
  Qb[(size_t)bl * 128 + h] = f2bf(q);
  Kb[(size_t)bl * 128 + h] = f2bf(k);
}

// ---------------- K1/K3: bf16 MFMA score tiles. PASS 0: histogram. PASS 1: collect.
// Block: 256 thr (4 waves), tile 128x128, K=128 staged once in 64KB LDS.
// LDS layout per tile row: 16 chunks of 16B, swizzled chunk c holds global chunk c^(row&7).
template<int PASS>
__global__ __launch_bounds__(256) void k_score(const ushort* __restrict__ Qb,
    const ushort* __restrict__ Kb, uint* __restrict__ ghist,
    const float* __restrict__ tcut, uint* __restrict__ ccnt, int* __restrict__ cidx) {
  __shared__ __align__(16) char lds[65536];   // A: [0,32768), B: [32768,65536)
  int b = blockIdx.x >> 6;
  int t = blockIdx.x & 63;
  int tm = t >> 3, tn = t & 7;
  int tid = threadIdx.x;
  const char* Aq = (const char*)(Qb + (size_t)b * 131072) + (size_t)tm * 128 * 256;
  const char* Bk = (const char*)(Kb + (size_t)b * 131072) + (size_t)tn * 128 * 256;
#pragma unroll
  for (int i = 0; i < 8; i++) {
    int slot = tid + 256 * i;       // 0..2047 = 128 rows x 16 chunks
    int row = slot >> 4;
    int c = slot & 15;
    int gc = c ^ (row & 7);         // swizzled source chunk
    *(uint4*)(lds + row * 256 + c * 16) = *(const uint4*)(Aq + row * 256 + gc * 16);
    *(uint4*)(lds + 32768 + row * 256 + c * 16) = *(const uint4*)(Bk + row * 256 + gc * 16);
  }
  __syncthreads();

  int w = tid >> 6, lane = tid & 63;
  int wm = (w >> 1) * 64, wn = (w & 1) * 64;   // 2x2 wave grid, 64x64 each
  int lr = lane & 15, lk = lane >> 4;
  f32x4 acc[4][4];
#pragma unroll
  for (int i = 0; i < 4; i++)
#pragma unroll
    for (int j = 0; j < 4; j++) acc[i][j] = (f32x4){0.f, 0.f, 0.f, 0.f};

#pragma unroll
  for (int ks = 0; ks < 4; ks++) {
    short8 af[4], bf[4];
#pragma unroll
    for (int f = 0; f < 4; f++) {
      int ra = wm + f * 16 + lr;
      int ca = (ks * 4 + lk) ^ (ra & 7);
      af[f] = *(const short8*)(lds + ra * 256 + ca * 16);
      int rb = wn + f * 16 + lr;
      int cb = (ks * 4 + lk) ^ (rb & 7);
      bf[f] = *(const short8*)(lds + 32768 + rb * 256 + cb * 16);
    }
#pragma unroll
    for (int fm = 0; fm < 4; fm++)
#pragma unroll
      for (int fn = 0; fn < 4; fn++)
        acc[fm][fn] = __builtin_amdgcn_mfma_f32_16x16x32_bf16(af[fm], bf[fn], acc[fm][fn], 0, 0, 0);
  }

  if (PASS == 0) {
    __syncthreads();                 // done reading tiles; reuse LDS as histogram
    uint* shist = (uint*)lds;
    for (int i = tid; i < NBINS; i += 256) shist[i] = 0;
    __syncthreads();
#pragma unroll
    for (int fm = 0; fm < 4; fm++)
#pragma unroll
      for (int fn = 0; fn < 4; fn++)
#pragma unroll
        for (int r = 0; r < 4; r++) {
          float v = acc[fm][fn][r] * SCALEF;
          uint u = __float_as_uint(v);
          u = (u & 0x80000000u) ? ~u : (u | 0x80000000u);   // order-preserving map
          atomicAdd(&shist[u >> 20], 1u);
        }
    __syncthreads();
    for (int i = tid; i < NBINS; i += 256) {
      uint c2 = shist[i];
      if (c2) atomicAdd(&ghist[b * NBINS + i], c2);
    }
  } else {
    float tc = tcut[b];
#pragma unroll
    for (int fm = 0; fm < 4; fm++)
#pragma unroll
      for (int fn = 0; fn < 4; fn++)
#pragma unroll
        for (int r = 0; r < 4; r++) {
          float v = acc[fm][fn][r] * SCALEF;
          if (v >= tc) {
            int mrow = tm * 128 + wm + fm * 16 + lk * 4 + r;   // C/D: row=(lane>>4)*4+reg
            int ncol = tn * 128 + wn + fn * 16 + lr;           //      col=lane&15
            uint pos = atomicAdd(&ccnt[b], 1u);
            if (pos < CAND_MAX) cidx[b * CAND_MAX + pos] = mrow * 1024 + ncol;
          }
        }
  }
}

// ---------------- K2: find per-batch threshold from histogram ----
__global__ __launch_bounds__(256) void k_thresh(const uint* __restrict__ ghist,
                                                float* __restrict__ tcut) {
  int b = blockIdx.x;
  int tid = threadIdx.x;
  __shared__ uint hsh[NBINS];
  __shared__ uint csuf[256];
  for (int i = tid; i < NBINS; i += 256) hsh[i] = ghist[b * NBINS + i];
  __syncthreads();
  uint s = 0;
#pragma unroll
  for (int i = 0; i < 16; i++) s += hsh[tid * 16 + i];
  csuf[tid] = s;
  __syncthreads();
  if (tid == 0) {                      // exclusive suffix over 256 chunk sums
    uint run = 0;
    for (int t2 = 255; t2 >= 0; t2--) { uint tmp = csuf[t2]; csuf[t2] = run; run += tmp; }
  }
  __syncthreads();
  uint above = csuf[tid];
  if (above < 64) {
    uint run = above;
    for (int i = 15; i >= 0; i--) {
      run += hsh[tid * 16 + i];
      if (run >= 64) {                 // bin containing the 64th-largest value
        uint umin = ((uint)(tid * 16 + i)) << 20;
        float lower = (umin & 0x80000000u) ? __uint_as_float(umin ^ 0x80000000u)
                                           : __uint_as_float(~umin);
        tcut[b] = lower - MARGIN;
        break;
      }
    }
  }
}

// ---------------- K4: exact fp32 rescore, top-64, softmax, fused MLP epilogue ----
__global__ __launch_bounds__(256) void k_final(const float* __restrict__ x,
    const float* __restrict__ Wq, const float* __restrict__ bq,
    const float* __restrict__ Wk, const float* __restrict__ bk,
    const float* __restrict__ phiW1, const float* __restrict__ phib1,
    const float* __restrict__ phiW2, const float* __restrict__ phib2,
    const float* __restrict__ xiW1, const float* __restrict__ xib1,
    const float* __restrict__ xiW2, const float* __restrict__ xib2,
    const float* __restrict__ rhoW1, const float* __restrict__ rhob1,
    const float* __restrict__ rhoW2, const float* __restrict__ rhob2,
    const uint* __restrict__ ccnt, const int* __restrict__ cidx,
    float* __restrict__ out) {
  int b = blockIdx.x;
  int tid = threadIdx.x;
  __shared__ float sW[6144];     // phase A: Wq[0:2048] Wk[2048:4096]; phase B: phiW1[0:2048] xiW1[2048:6144]
  __shared__ float sB[256];      // phase A: bq,bk; phase B: phib1,xib1
  __shared__ float cvals[CAND_MAX];
  __shared__ int   cidxs[CAND_MAX];
  __shared__ float sel_v[64], sel_w[64];
  __shared__ int   sel_l[64], sel_m[64];
  __shared__ float rv[4]; __shared__ int ri[4]; __shared__ int rs[4];
  __shared__ float hsv[128], hpv[128];
  __shared__ float xrow[32];
  __shared__ float vec1[128], vec2[128];
  __shared__ float wsums[2];

  for (int i = tid; i < 2048; i += 256) { sW[i] = Wq[i]; sW[2048 + i] = Wk[i]; }
  if (tid < 128) { sB[tid] = bq[tid]; sB[128 + tid] = bk[tid]; }
  uint cnt0 = ccnt[b];
  int cnt = cnt0 > CAND_MAX ? CAND_MAX : (int)cnt0;
  for (int i = tid; i < cnt; i += 256) cidxs[i] = cidx[b * CAND_MAX + i];
  __syncthreads();

  // exact fp32 rescore of candidates (recompute q,k from x to avoid fp32 Q/K storage)
  for (int j = tid; j < cnt; j += 256) {
    int fi = cidxs[j];
    int l = fi >> 10, m = fi & 1023;
    const float* xi = x + ((size_t)b * 1024 + l) * 16;
    const float* xj = x + ((size_t)b * 1024 + m) * 16;
    float xl[16], xm[16];
#pragma unroll
    for (int d = 0; d < 16; d += 4) {
      *(float4*)&xl[d] = *(const float4*)&xi[d];
      *(float4*)&xm[d] = *(const float4*)&xj[d];
    }
    float s = 0.f;
    for (int h = 0; h < 128; h++) {
      float q = sB[h], kk = sB[128 + h];
#pragma unroll
      for (int d = 0; d < 16; d++) {
        q += xl[d] * sW[d * 128 + h];
        kk += xm[d] * sW[2048 + d * 128 + h];
      }
      s += q * kk;
    }
    cvals[j] = s * SCALEF;
  }
  for (int j = cnt + tid; j < CAND_MAX; j += 256) { cvals[j] = -1e30f; cidxs[j] = 0x7fffffff; }
  __syncthreads();

  // iterative exact top-64 (descending), tie-break: smaller flat index (matches top_k)
  for (int it = 0; it < 64; it++) {
    float bv = -1e30f; int bidx = 0x7fffffff; int bslot = -1;
    for (int j = tid; j < CAND_MAX; j += 256) {
      float v = cvals[j]; int ix = cidxs[j];
      if (v > bv || (v == bv && ix < bidx)) { bv = v; bidx = ix; bslot = j; }
    }
#pragma unroll
    for (int off = 32; off > 0; off >>= 1) {
      float ov = __shfl_down(bv, off);
      int oi = __shfl_down(bidx, off);
      int os = __shfl_down(bslot, off);
      if (ov > bv || (ov == bv && oi < bidx)) { bv = ov; bidx = oi; bslot = os; }
    }
    if ((tid & 63) == 0) { int wi = tid >> 6; rv[wi] = bv; ri[wi] = bidx; rs[wi] = bslot; }
    __syncthreads();
    if (tid == 0) {
      for (int wi = 1; wi < 4; wi++)
        if (rv[wi] > bv || (rv[wi] == bv && ri[wi] < bidx)) { bv = rv[wi]; bidx = ri[wi]; bslot = rs[wi]; }
      sel_v[it] = bv;
      sel_l[it] = bidx >> 10;
      sel_m[it] = bidx & 1023;
      cvals[bslot] = -1e30f;
    }
    __syncthreads();
  }

  // softmax over the 64 selected (sel_v[0] is the max)
  if (tid < 64) {
    float e = expf(sel_v[tid] - sel_v[0]);
    float ssum = e;
#pragma unroll
    for (int off = 1; off < 64; off <<= 1) ssum += __shfl_xor(ssum, off);
    sel_w[tid] = e / ssum;
  }
  __syncthreads();

  // feature phase: weighted hidden accumulation (linearity: move W2 out of the sum)
  for (int i = tid; i < 2048; i += 256) sW[i] = phiW1[i];
  for (int i = tid; i < 4096; i += 256) sW[2048 + i] = xiW1[i];
  if (tid < 128) { sB[tid] = phib1[tid]; sB[128 + tid] = xib1[tid]; hsv[tid] = 0.f; hpv[tid] = 0.f; }
  if (tid == 0) { wsums[0] = 0.f; wsums[1] = 0.f; }
  __syncthreads();

  for (int j = 0; j < 64; j++) {
    int l = sel_l[j], m = sel_m[j];
    float wj = sel_w[j];
    if (tid < 16) xrow[tid] = x[((size_t)b * 1024 + l) * 16 + tid];
    else if (tid < 32) xrow[tid] = x[((size_t)b * 1024 + m) * 16 + (tid - 16)];
    if (tid == 0) wsums[l == m ? 0 : 1] += wj;
    __syncthreads();
    if (tid < 128) {
      float a;
      if (l == m) {
        a = sB[tid];
#pragma unroll
        for (int d = 0; d < 16; d++) a += xrow[d] * sW[d * 128 + tid];
        a = fmaxf(a, 0.f);
        hsv[tid] += wj * a;
      } else {
        a = sB[128 + tid];
#pragma unroll
        for (int d = 0; d < 32; d++) a += xrow[d] * sW[2048 + d * 128 + tid];
        a = fmaxf(a, 0.f);
        hpv[tid] += wj * a;
      }
    }
    __syncthreads();
  }

  if (tid < 128) {
    float p = wsums[0] * phib2[tid] + wsums[1] * xib2[tid];
    for (int h = 0; h < 128; h++) p += hsv[h] * phiW2[h * 128 + tid] + hpv[h] * xiW2[h * 128 + tid];
    vec1[tid] = p;
  }
  __syncthreads();
  if (tid < 128) {
    float r = rhob1[tid];
    for (int h = 0; h < 128; h++) r += vec1[h] * rhoW1[h * 128 + tid];
    vec2[tid] = fmaxf(r, 0.f);
  }
  __syncthreads();
  if (tid < 128) {
    float o = rhob2[tid];
    for (int h = 0; h < 128; h++) o += vec2[h] * rhoW2[h * 128 + tid];
    out[(size_t)b * 128 + tid] = o;
  }
}

// ---------------- launch ----------------
extern "C" void kernel_launch(void* const* d_in, const int* in_sizes, int n_in,
                              void* d_out, int out_size, void* d_ws, size_t ws_size,
                              hipStream_t stream) {
  (void)in_sizes; (void)n_in; (void)out_size; (void)ws_size;
  const float* x     = (const float*)d_in[0];
  const float* Wq    = (const float*)d_in[1];
  const float* bq    = (const float*)d_in[2];
  const float* Wk    = (const float*)d_in[3];
  const float* bk    = (const float*)d_in[4];
  const float* phiW1 = (const float*)d_in[5];
  const float* phib1 = (const float*)d_in[6];
  const float* phiW2 = (const float*)d_in[7];
  const float* phib2 = (const float*)d_in[8];
  const float* xiW1  = (const float*)d_in[9];
  const float* xib1  = (const float*)d_in[10];
  const float* xiW2  = (const float*)d_in[11];
  const float* xib2  = (const float*)d_in[12];
  const float* rhoW1 = (const float*)d_in[13];
  const float* rhob1 = (const float*)d_in[14];
  const float* rhoW2 = (const float*)d_in[15];
  const float* rhob2 = (const float*)d_in[16];

  // workspace layout (~34.1 MB total)
  char* ws = (char*)d_ws;
  ushort* Qb  = (ushort*)(ws);                  // 16,777,216 B
  ushort* Kb  = (ushort*)(ws + 16777216);       // 16,777,216 B
  uint*   hist = (uint*)(ws + 33554432);        //  1,048,576 B
  uint*   ccnt = (uint*)(ws + 34603008);        //        256 B
  float*  tcut = (float*)(ws + 34603264);       //        256 B
  int*    cidx = (int*)(ws + 34603520);         //  1,048,576 B

  hipMemsetAsync(ws + 33554432, 0, 1048576 + 256, stream);   // hist + ccnt

  k_proj<<<64 * 1024, 128, 0, stream>>>(x, Wq, bq, Wk, bk, Qb, Kb);
  k_score<0><<<64 * 64, 256, 0, stream>>>(Qb, Kb, hist, nullptr, nullptr, nullptr);
  k_thresh<<<64, 256, 0, stream>>>(hist, tcut);
  k_score<1><<<64 * 64, 256, 0, stream>>>(Qb, Kb, hist, tcut, ccnt, cidx);
  k_final<<<64, 256, 0, stream>>>(x, Wq, bq, Wk, bk,
                                  phiW1, phib1, phiW2, phib2,
                                  xiW1, xib1, xiW2, xib2,
                                  rhoW1, rhob1, rhoW2, rhob2,
                                  (const uint*)ccnt, cidx, (float*)d_out);
}